// Round 6
// baseline (357.659 us; speedup 1.0000x reference)
//
#include <hip/hip_runtime.h>
#include <math.h>

// Fused LSTM, bf16 MFMA, register-resident gx (round 6).
// B=1024,T=256,D=128,H=64,G=256,O=128. 64 blocks x 256 thr; block owns 16
// batches for the whole scan. Wave w owns gate cols {64q+16w+lq}; i,f,g,o for
// a cell land in one lane; c-state in registers.
// KEY (R6): the x-projection (4 of 6 MFMAs, 4 of 6 ds_reads per step) has no
// sequential dependence -> compute gx = bias + x.Wih^T for a whole 8-step
// chunk into REGISTERS at the chunk boundary (latency-tolerant burst).
// The barrier-gated inner step is only: 2 ds_read_b128 (h frags) -> 2-MFMA
// chain -> activations -> h write -> LDS-only barrier.
constexpr int B = 1024, T = 256, D = 128, H = 64, O = 128;
constexpr int BQ = 16;
constexpr int NBLK = B / BQ;   // 64 blocks
constexpr int TC = 8;          // timesteps per chunk
constexpr int NCH = T / TC;    // 32 chunks

typedef __attribute__((ext_vector_type(8))) short short8;
typedef __attribute__((ext_vector_type(4))) float f32x4;

__device__ __forceinline__ unsigned short f2bf(float f) {
    union { float f; unsigned u; } v; v.f = f;
    return (unsigned short)((v.u + 0x7FFF + ((v.u >> 16) & 1)) >> 16);  // RNE
}
__device__ __forceinline__ float frcp(float x) { return __builtin_amdgcn_rcpf(x); }
__device__ __forceinline__ float sigmoidf_(float x) {
    return frcp(1.0f + __expf(-x));
}
__device__ __forceinline__ float tanhf_(float x) {
    return fmaf(2.0f, frcp(1.0f + __expf(-2.0f * x)), -1.0f);  // overflow-safe
}
// LDS-visibility barrier that does NOT drain outstanding global loads.
__device__ __forceinline__ void lds_barrier() {
    asm volatile("s_waitcnt lgkmcnt(0)\n\ts_barrier" ::: "memory");
}

__global__ __launch_bounds__(256, 1)
void lstm_fused(const float* __restrict__ x, const float* __restrict__ Wih,
                const float* __restrict__ Whh, const float* __restrict__ bih,
                const float* __restrict__ bhh, const float* __restrict__ Wo,
                const float* __restrict__ bo, float* __restrict__ out)
{
    // x A-frags, SINGLE buffer (write -> barrier -> read, all at boundary).
    // slab layout per tt: byte off = c*1024 + ((fraglane*16) ^ (c*32))
    __shared__ unsigned short xfrag[TC][4 * 64 * 8];   // 32 KB
    __shared__ unsigned short hfrag[2][2 * 64 * 8];    // 4 KB
    __shared__ float hf[BQ][H];                        // 4 KB

    const int tid  = threadIdx.x;
    const int lane = tid & 63;
    const int w    = tid >> 6;
    const int lq   = lane & 15;
    const int qd   = lane >> 4;
    const int b0   = blockIdx.x * BQ;

    // ---- weight B-fragments (constant over t) ----
    short8 wih_f[4][4];
    short8 whh_f[4][2];
    float  bias[4];
    #pragma unroll
    for (int q = 0; q < 4; ++q) {
        const int n = 64 * q + 16 * w + lq;
        #pragma unroll
        for (int c = 0; c < 4; ++c) {
            const float* p = Wih + (size_t)n * D + 32 * c + 8 * qd;
            short8 v;
            #pragma unroll
            for (int j = 0; j < 8; ++j) v[j] = (short)f2bf(p[j]);
            wih_f[q][c] = v;
        }
        #pragma unroll
        for (int c = 0; c < 2; ++c) {
            const float* p = Whh + (size_t)n * H + 32 * c + 8 * qd;
            short8 v;
            #pragma unroll
            for (int j = 0; j < 8; ++j) v[j] = (short)f2bf(p[j]);
            whh_f[q][c] = v;
        }
        bias[q] = bih[n] + bhh[n];
    }

    // ---- staging geometry: thread stages x[b0+ms][t][8*kslot .. +8) ----
    const int ms    = tid >> 4;
    const int kslot = tid & 15;
    const int c_p   = kslot >> 2;
    const int q_p   = kslot & 3;
    const int l_p   = (q_p << 4) | ms;
    const int xoff  = c_p * 1024 + ((l_p * 16) ^ (c_p * 32));  // bytes in slab
    const float* xrow = x + (size_t)(b0 + ms) * T * D + 8 * kslot;

    // frag-read byte offsets for this lane
    int xro[4], hro[2];
    #pragma unroll
    for (int c = 0; c < 4; ++c) xro[c] = c * 1024 + ((lane * 16) ^ (c * 32));
    #pragma unroll
    for (int c = 0; c < 2; ++c) hro[c] = c * 1024 + lane * 16;

    // h producer scatter target (verified R5): per r add r*8 shorts
    const int hrow_base = (w >> 1) * 512 +
                          (16 * ((2 * w + (lq >> 3)) & 3) + 4 * qd) * 8 + (lq & 7);

    // ---- zero hfrag ----
    for (int i = tid; i < 2 * 2 * 64 * 8 / 2; i += 256)
        ((unsigned int*)hfrag)[i] = 0;

    // ---- load + commit chunk 0 ----
    float4 pf[2 * TC];
    #pragma unroll
    for (int tt = 0; tt < TC; ++tt) {
        const float* p = xrow + (size_t)tt * D;
        pf[2 * tt]     = *(const float4*)p;
        pf[2 * tt + 1] = *(const float4*)(p + 4);
    }
    #pragma unroll
    for (int tt = 0; tt < TC; ++tt) {
        float4 a = pf[2 * tt], bv = pf[2 * tt + 1];
        short8 v;
        v[0] = (short)f2bf(a.x);  v[1] = (short)f2bf(a.y);
        v[2] = (short)f2bf(a.z);  v[3] = (short)f2bf(a.w);
        v[4] = (short)f2bf(bv.x); v[5] = (short)f2bf(bv.y);
        v[6] = (short)f2bf(bv.z); v[7] = (short)f2bf(bv.w);
        *(short8*)((char*)&xfrag[tt][0] + xoff) = v;
    }
    __syncthreads();

    // ---- gx for chunk 0 into registers; then issue chunk-1 loads ----
    f32x4 gxacc[TC][4];
    #pragma unroll
    for (int tt = 0; tt < TC; ++tt) {
        short8 xf[4];
        #pragma unroll
        for (int c = 0; c < 4; ++c)
            xf[c] = *(const short8*)((char*)&xfrag[tt][0] + xro[c]);
        #pragma unroll
        for (int q = 0; q < 4; ++q) {
            f32x4 a = {bias[q], bias[q], bias[q], bias[q]};
            #pragma unroll
            for (int c = 0; c < 4; ++c)
                a = __builtin_amdgcn_mfma_f32_16x16x32_bf16(xf[c], wih_f[q][c], a, 0, 0, 0);
            gxacc[tt][q] = a;
        }
    }
    #pragma unroll
    for (int tt = 0; tt < TC; ++tt) {
        const float* p = xrow + (size_t)(TC + tt) * D;
        pf[2 * tt]     = *(const float4*)p;
        pf[2 * tt + 1] = *(const float4*)(p + 4);
    }

    float cst[4] = {0.f, 0.f, 0.f, 0.f};
    float hlast[4];

    for (int ch = 0; ch < NCH; ++ch) {
        // ---- inner loop: recurrence only ----
        #pragma unroll
        for (int tt = 0; tt < TC; ++tt) {
            const int hcur = tt & 1, hnxt = hcur ^ 1;

            short8 hfr[2];
            #pragma unroll
            for (int c = 0; c < 2; ++c)
                hfr[c] = *(const short8*)((char*)&hfrag[hcur][0] + hro[c]);

            f32x4 acc[4];
            #pragma unroll
            for (int q = 0; q < 4; ++q) {
                f32x4 a = gxacc[tt][q];
                #pragma unroll
                for (int c = 0; c < 2; ++c)
                    a = __builtin_amdgcn_mfma_f32_16x16x32_bf16(hfr[c], whh_f[q][c], a, 0, 0, 0);
                acc[q] = a;
            }

            #pragma unroll
            for (int r = 0; r < 4; ++r) {
                float gi = sigmoidf_(acc[0][r]);
                float gf = sigmoidf_(acc[1][r]);
                float gg = tanhf_  (acc[2][r]);
                float go = sigmoidf_(acc[3][r]);
                float c2 = fmaf(gf, cst[r], gi * gg);
                cst[r] = c2;
                float hv = go * tanhf_(c2);
                hlast[r] = hv;
                hfrag[hnxt][hrow_base + r * 8] = f2bf(hv);
            }

            lds_barrier();
        }

        // ---- chunk boundary ----
        if (ch + 1 < NCH) {
            // commit chunk ch+1 (loads issued a full chunk ago)
            #pragma unroll
            for (int tt = 0; tt < TC; ++tt) {
                float4 a = pf[2 * tt], bv = pf[2 * tt + 1];
                short8 v;
                v[0] = (short)f2bf(a.x);  v[1] = (short)f2bf(a.y);
                v[2] = (short)f2bf(a.z);  v[3] = (short)f2bf(a.w);
                v[4] = (short)f2bf(bv.x); v[5] = (short)f2bf(bv.y);
                v[6] = (short)f2bf(bv.z); v[7] = (short)f2bf(bv.w);
                *(short8*)((char*)&xfrag[tt][0] + xoff) = v;
            }
            // issue chunk ch+2 loads (in flight across the gx burst + chunk)
            {
                const int ch2 = (ch + 2 < NCH) ? ch + 2 : NCH - 1;
                #pragma unroll
                for (int tt = 0; tt < TC; ++tt) {
                    const float* p = xrow + ((size_t)ch2 * TC + tt) * D;
                    pf[2 * tt]     = *(const float4*)p;
                    pf[2 * tt + 1] = *(const float4*)(p + 4);
                }
            }
            lds_barrier();
            // gx burst for chunk ch+1: 32 ds_read_b128 + 128 MFMA, no
            // barrier-gating, latency overlapped by issue depth
            #pragma unroll
            for (int tt = 0; tt < TC; ++tt) {
                short8 xf[4];
                #pragma unroll
                for (int c = 0; c < 4; ++c)
                    xf[c] = *(const short8*)((char*)&xfrag[tt][0] + xro[c]);
                #pragma unroll
                for (int q = 0; q < 4; ++q) {
                    f32x4 a = {bias[q], bias[q], bias[q], bias[q]};
                    #pragma unroll
                    for (int c = 0; c < 4; ++c)
                        a = __builtin_amdgcn_mfma_f32_16x16x32_bf16(xf[c], wih_f[q][c], a, 0, 0, 0);
                    gxacc[tt][q] = a;
                }
            }
        }
    }

    // ---- epilogue: logits = relu(h) Wo^T + bo ; log_softmax over O=128 ----
    #pragma unroll
    for (int r = 0; r < 4; ++r) hf[4 * qd + r][16 * w + lq] = hlast[r];
    __syncthreads();

    for (int it = 0; it < 4; ++it) {
        const int m = 4 * it + w;
        float l0 = bo[lane], l1 = bo[lane + 64];
        const float* w0 = Wo + (size_t)lane * H;
        const float* w1 = Wo + (size_t)(lane + 64) * H;
        #pragma unroll
        for (int k = 0; k < H; ++k) {
            float rh = fmaxf(hf[m][k], 0.0f);
            l0 += rh * w0[k];
            l1 += rh * w1[k];
        }
        float mx = fmaxf(l0, l1);
        #pragma unroll
        for (int sh = 32; sh > 0; sh >>= 1) mx = fmaxf(mx, __shfl_xor(mx, sh));
        float e = __expf(l0 - mx) + __expf(l1 - mx);
        #pragma unroll
        for (int sh = 32; sh > 0; sh >>= 1) e += __shfl_xor(e, sh);
        float lse = mx + __logf(e);
        float* op = out + (size_t)(b0 + m) * O;
        op[lane]      = l0 - lse;
        op[lane + 64] = l1 - lse;
    }
}

extern "C" void kernel_launch(void* const* d_in, const int* in_sizes, int n_in,
                              void* d_out, int out_size, void* d_ws, size_t ws_size,
                              hipStream_t stream) {
    const float* x   = (const float*)d_in[0];
    const float* Wih = (const float*)d_in[1];
    const float* Whh = (const float*)d_in[2];
    const float* bih = (const float*)d_in[3];
    const float* bhh = (const float*)d_in[4];
    const float* Wo  = (const float*)d_in[5];
    const float* bo  = (const float*)d_in[6];
    lstm_fused<<<dim3(NBLK), dim3(256), 0, stream>>>(
        x, Wih, Whh, bih, bhh, Wo, bo, (float*)d_out);
}

// Round 7
// 353.412 us; speedup vs baseline: 1.0120x; 1.0120x over previous
//
#include <hip/hip_runtime.h>
#include <math.h>

// Fused LSTM, bf16 MFMA, gx interleaved into the scan (round 7).
// B=1024,T=256,D=128,H=64,G=256,O=128. 64 blocks x 256 thr; block owns 16
// batches. Wave w owns gate cols {64q+16w+lq}; i,f,g,o of a cell in one lane;
// c-state in registers. gxacc[tt] (gx = bias + x.Wih^T) lives in registers and
// is ROTATED: consumed at step tt of chunk ch, recomputed in the same step for
// chunk ch+1 from xfrag (independent work -> fills MFMA/stall windows; the
// separate chunk-boundary gx burst is gone). hfrag is XOR-swizzled (granule
// g ^= (g>>2)&3): producer b16 scatter ~2-way (free), consumer b128 clean.
constexpr int B = 1024, T = 256, D = 128, H = 64, O = 128;
constexpr int BQ = 16;
constexpr int NBLK = B / BQ;   // 64 blocks
constexpr int TC = 8;          // timesteps per chunk
constexpr int NCH = T / TC;    // 32 chunks

typedef __attribute__((ext_vector_type(8))) short short8;
typedef __attribute__((ext_vector_type(4))) float f32x4;

__device__ __forceinline__ unsigned short f2bf(float f) {
    union { float f; unsigned u; } v; v.f = f;
    return (unsigned short)((v.u + 0x7FFF + ((v.u >> 16) & 1)) >> 16);  // RNE
}
__device__ __forceinline__ float frcp(float x) { return __builtin_amdgcn_rcpf(x); }
__device__ __forceinline__ float sigmoidf_(float x) {
    return frcp(1.0f + __expf(-x));
}
__device__ __forceinline__ float tanhf_(float x) {
    return fmaf(2.0f, frcp(1.0f + __expf(-2.0f * x)), -1.0f);  // overflow-safe
}
// LDS-visibility barrier that does NOT drain outstanding global loads.
__device__ __forceinline__ void lds_barrier() {
    asm volatile("s_waitcnt lgkmcnt(0)\n\ts_barrier" ::: "memory");
}

__global__ __launch_bounds__(256, 1)
void lstm_fused(const float* __restrict__ x, const float* __restrict__ Wih,
                const float* __restrict__ Whh, const float* __restrict__ bih,
                const float* __restrict__ bhh, const float* __restrict__ Wo,
                const float* __restrict__ bo, float* __restrict__ out)
{
    // xfrag: SINGLE buffer holding x(ch+1) during chunk ch (gx for ch is
    // already in regs). slab byte off = c*1024 + ((fraglane*16) ^ (c*32)).
    __shared__ unsigned short xfrag[TC][4 * 64 * 8];   // 32 KB
    __shared__ unsigned short hfrag[2][2 * 64 * 8];    // 4 KB (swizzled)
    __shared__ float hf[BQ][H];                        // 4 KB

    const int tid  = threadIdx.x;
    const int lane = tid & 63;
    const int w    = tid >> 6;
    const int lq   = lane & 15;
    const int qd   = lane >> 4;
    const int b0   = blockIdx.x * BQ;

    // ---- weight B-fragments (constant over t) ----
    short8 wih_f[4][4];
    short8 whh_f[4][2];
    float  bias[4];
    #pragma unroll
    for (int q = 0; q < 4; ++q) {
        const int n = 64 * q + 16 * w + lq;
        #pragma unroll
        for (int c = 0; c < 4; ++c) {
            const float* p = Wih + (size_t)n * D + 32 * c + 8 * qd;
            short8 v;
            #pragma unroll
            for (int j = 0; j < 8; ++j) v[j] = (short)f2bf(p[j]);
            wih_f[q][c] = v;
        }
        #pragma unroll
        for (int c = 0; c < 2; ++c) {
            const float* p = Whh + (size_t)n * H + 32 * c + 8 * qd;
            short8 v;
            #pragma unroll
            for (int j = 0; j < 8; ++j) v[j] = (short)f2bf(p[j]);
            whh_f[q][c] = v;
        }
        bias[q] = bih[n] + bhh[n];
    }

    // ---- staging geometry: thread stages x[b0+ms][t][8*kslot .. +8) ----
    const int ms    = tid >> 4;
    const int kslot = tid & 15;
    const int c_p   = kslot >> 2;
    const int q_p   = kslot & 3;
    const int l_p   = (q_p << 4) | ms;
    const int xoff  = c_p * 1024 + ((l_p * 16) ^ (c_p * 32));  // bytes
    const float* xrow = x + (size_t)(b0 + ms) * T * D + 8 * kslot;

    // x frag-read byte offsets (XOR swizzle, as R5/R6)
    int xro[4];
    #pragma unroll
    for (int c = 0; c < 4; ++c) xro[c] = c * 1024 + ((lane * 16) ^ (c * 32));

    // h frag-read byte offsets, granule-swizzled: g' = g ^ ((g>>2)&3)
    const int hg = lane ^ ((lane >> 2) & 3);
    int hro[2];
    #pragma unroll
    for (int c = 0; c < 2; ++c) hro[c] = c * 1024 + hg * 16;

    // h producer target (shorts): cell (m=4qd+r, j=16w+lq) -> chunk j>>5,
    // granule 16*((j>>3)&3) + 4qd + (r^qd)   [swizzle applied], offset j&7
    const int j    = 16 * w + lq;
    const int cjs  = (j >> 5) * 512;          // shorts
    const int gba  = ((j >> 3) & 3) * 16 + 4 * qd;
    const int joff = j & 7;

    // ---- zero hfrag (both buffers) ----
    for (int i = tid; i < 1024; i += 256) ((unsigned int*)hfrag)[i] = 0;

    // ---- prologue: xfrag=x(0) -> gx(0) -> xfrag=x(1), pf=x(2) ----
    float4 pf[2 * TC];
    #pragma unroll
    for (int tt = 0; tt < TC; ++tt) {
        const float* p = xrow + (size_t)tt * D;
        pf[2 * tt]     = *(const float4*)p;
        pf[2 * tt + 1] = *(const float4*)(p + 4);
    }
    #pragma unroll
    for (int tt = 0; tt < TC; ++tt) {
        float4 a = pf[2 * tt], bv = pf[2 * tt + 1];
        short8 v;
        v[0] = (short)f2bf(a.x);  v[1] = (short)f2bf(a.y);
        v[2] = (short)f2bf(a.z);  v[3] = (short)f2bf(a.w);
        v[4] = (short)f2bf(bv.x); v[5] = (short)f2bf(bv.y);
        v[6] = (short)f2bf(bv.z); v[7] = (short)f2bf(bv.w);
        *(short8*)((char*)&xfrag[tt][0] + xoff) = v;
    }
    __syncthreads();

    f32x4 gxacc[TC][4];
    #pragma unroll
    for (int tt = 0; tt < TC; ++tt) {
        short8 xf[4];
        #pragma unroll
        for (int c = 0; c < 4; ++c)
            xf[c] = *(const short8*)((char*)&xfrag[tt][0] + xro[c]);
        #pragma unroll
        for (int q = 0; q < 4; ++q) {
            f32x4 a = {bias[q], bias[q], bias[q], bias[q]};
            #pragma unroll
            for (int c = 0; c < 4; ++c)
                a = __builtin_amdgcn_mfma_f32_16x16x32_bf16(xf[c], wih_f[q][c], a, 0, 0, 0);
            gxacc[tt][q] = a;
        }
    }
    #pragma unroll
    for (int tt = 0; tt < TC; ++tt) {         // load x(chunk 1)
        const float* p = xrow + (size_t)(TC + tt) * D;
        pf[2 * tt]     = *(const float4*)p;
        pf[2 * tt + 1] = *(const float4*)(p + 4);
    }
    lds_barrier();                            // gx(0) reads of xfrag done
    #pragma unroll
    for (int tt = 0; tt < TC; ++tt) {         // commit x(1) -> xfrag
        float4 a = pf[2 * tt], bv = pf[2 * tt + 1];
        short8 v;
        v[0] = (short)f2bf(a.x);  v[1] = (short)f2bf(a.y);
        v[2] = (short)f2bf(a.z);  v[3] = (short)f2bf(a.w);
        v[4] = (short)f2bf(bv.x); v[5] = (short)f2bf(bv.y);
        v[6] = (short)f2bf(bv.z); v[7] = (short)f2bf(bv.w);
        *(short8*)((char*)&xfrag[tt][0] + xoff) = v;
    }
    #pragma unroll
    for (int tt = 0; tt < TC; ++tt) {         // issue x(chunk 2)
        const float* p = xrow + (size_t)(2 * TC + tt) * D;
        pf[2 * tt]     = *(const float4*)p;
        pf[2 * tt + 1] = *(const float4*)(p + 4);
    }
    lds_barrier();                            // commit visible (+ h zeros)

    float cst[4] = {0.f, 0.f, 0.f, 0.f};
    float hlast[4];

    for (int ch = 0; ch < NCH; ++ch) {
        #pragma unroll
        for (int tt = 0; tt < TC; ++tt) {
            const int hcur = tt & 1, hnxt = hcur ^ 1;

            short8 hfr[2];
            #pragma unroll
            for (int c = 0; c < 2; ++c)
                hfr[c] = *(const short8*)((char*)&hfrag[hcur][0] + hro[c]);
            short8 xf[4];   // next-chunk x (independent of recurrence)
            #pragma unroll
            for (int c = 0; c < 4; ++c)
                xf[c] = *(const short8*)((char*)&xfrag[tt][0] + xro[c]);

            // recurrence MFMAs (critical path)
            f32x4 acc[4];
            #pragma unroll
            for (int q = 0; q < 4; ++q) {
                f32x4 a = gxacc[tt][q];
                #pragma unroll
                for (int c = 0; c < 2; ++c)
                    a = __builtin_amdgcn_mfma_f32_16x16x32_bf16(hfr[c], whh_f[q][c], a, 0, 0, 0);
                acc[q] = a;
            }

            // gx for chunk ch+1, step tt (fills stall windows; WAR on gxacc)
            #pragma unroll
            for (int q = 0; q < 4; ++q) {
                f32x4 a = {bias[q], bias[q], bias[q], bias[q]};
                #pragma unroll
                for (int c = 0; c < 4; ++c)
                    a = __builtin_amdgcn_mfma_f32_16x16x32_bf16(xf[c], wih_f[q][c], a, 0, 0, 0);
                gxacc[tt][q] = a;
            }

            // activations + state update
            #pragma unroll
            for (int r = 0; r < 4; ++r) {
                float gi = sigmoidf_(acc[0][r]);
                float gf = sigmoidf_(acc[1][r]);
                float gg = tanhf_  (acc[2][r]);
                float go = sigmoidf_(acc[3][r]);
                float c2 = fmaf(gf, cst[r], gi * gg);
                cst[r] = c2;
                float hv = go * tanhf_(c2);
                hlast[r] = hv;
                hfrag[hnxt][cjs + (gba + (r ^ qd)) * 8 + joff] = f2bf(hv);
            }

            lds_barrier();
        }

        // ---- chunk boundary: commit x(ch+2), issue x(ch+3) ----
        if (ch + 1 < NCH) {
            #pragma unroll
            for (int tt = 0; tt < TC; ++tt) {
                float4 a = pf[2 * tt], bv = pf[2 * tt + 1];
                short8 v;
                v[0] = (short)f2bf(a.x);  v[1] = (short)f2bf(a.y);
                v[2] = (short)f2bf(a.z);  v[3] = (short)f2bf(a.w);
                v[4] = (short)f2bf(bv.x); v[5] = (short)f2bf(bv.y);
                v[6] = (short)f2bf(bv.z); v[7] = (short)f2bf(bv.w);
                *(short8*)((char*)&xfrag[tt][0] + xoff) = v;
            }
            const int ch3 = (ch + 3 < NCH) ? ch + 3 : NCH - 1;
            #pragma unroll
            for (int tt = 0; tt < TC; ++tt) {
                const float* p = xrow + ((size_t)ch3 * TC + tt) * D;
                pf[2 * tt]     = *(const float4*)p;
                pf[2 * tt + 1] = *(const float4*)(p + 4);
            }
            lds_barrier();
        }
    }

    // ---- epilogue: logits = relu(h) Wo^T + bo ; log_softmax over O=128 ----
    #pragma unroll
    for (int r = 0; r < 4; ++r) hf[4 * qd + r][16 * w + lq] = hlast[r];
    __syncthreads();

    for (int it = 0; it < 4; ++it) {
        const int m = 4 * it + w;
        float l0 = bo[lane], l1 = bo[lane + 64];
        const float* w0 = Wo + (size_t)lane * H;
        const float* w1 = Wo + (size_t)(lane + 64) * H;
        #pragma unroll
        for (int k = 0; k < H; ++k) {
            float rh = fmaxf(hf[m][k], 0.0f);
            l0 += rh * w0[k];
            l1 += rh * w1[k];
        }
        float mx = fmaxf(l0, l1);
        #pragma unroll
        for (int sh = 32; sh > 0; sh >>= 1) mx = fmaxf(mx, __shfl_xor(mx, sh));
        float e = __expf(l0 - mx) + __expf(l1 - mx);
        #pragma unroll
        for (int sh = 32; sh > 0; sh >>= 1) e += __shfl_xor(e, sh);
        float lse = mx + __logf(e);
        float* op = out + (size_t)(b0 + m) * O;
        op[lane]      = l0 - lse;
        op[lane + 64] = l1 - lse;
    }
}

extern "C" void kernel_launch(void* const* d_in, const int* in_sizes, int n_in,
                              void* d_out, int out_size, void* d_ws, size_t ws_size,
                              hipStream_t stream) {
    const float* x   = (const float*)d_in[0];
    const float* Wih = (const float*)d_in[1];
    const float* Whh = (const float*)d_in[2];
    const float* bih = (const float*)d_in[3];
    const float* bhh = (const float*)d_in[4];
    const float* Wo  = (const float*)d_in[5];
    const float* bo  = (const float*)d_in[6];
    lstm_fused<<<dim3(NBLK), dim3(256), 0, stream>>>(
        x, Wih, Whh, bih, bhh, Wo, bo, (float*)d_out);
}

// Round 8
// 283.066 us; speedup vs baseline: 1.2635x; 1.2485x over previous
//
#include <hip/hip_runtime.h>
#include <math.h>

// Fused LSTM, bf16 MFMA, BQ=4 on 256 CUs, 1 cell/thread activations (round 8).
// B=1024,T=256,D=128,H=64,G=256,O=128. 256 blocks x 256 thr (4 waves).
// Block owns 4 batches. Wave w owns gate cols {64q+16w+lq}. MFMA C-layout
// leaves the 4 batches' gates in lanes 0-15 -> redistribute via INTRA-WAVE
// LDS round-trip (no barrier: producer wave == consumer wave, lgkmcnt only).
// Each thread then owns ONE cell (b=qd, j=16w+lq): 10 trans/wave-step (was 40).
// gx = bias + x.Wih^T precomputed per 8-step chunk with TS-PACKED MFMAs
// (M-rows = 4ts x 4batch) and round-tripped into 32 f32 regs/thread.
// Inner step: 2 ds_read_b128 (h) -> 8 MFMA -> 4 masked b128 gate writes ->
// 4 b32 reads -> activations -> 1 ds_write_b16 -> ONE lds_barrier.
constexpr int B = 1024, T = 256, D = 128, H = 64, O = 128;
constexpr int BQ = 4;
constexpr int NBLK = B / BQ;   // 256 blocks
constexpr int TC = 8;          // timesteps per chunk
constexpr int NCH = T / TC;    // 32 chunks

typedef __attribute__((ext_vector_type(8))) short short8;
typedef __attribute__((ext_vector_type(4))) float f32x4;

__device__ __forceinline__ unsigned short f2bf(float f) {
    union { float f; unsigned u; } v; v.f = f;
    return (unsigned short)((v.u + 0x7FFF + ((v.u >> 16) & 1)) >> 16);  // RNE
}
__device__ __forceinline__ float frcp(float x) { return __builtin_amdgcn_rcpf(x); }
__device__ __forceinline__ float sigmoidf_(float x) {
    return frcp(1.0f + __expf(-x));
}
__device__ __forceinline__ float tanhf_(float x) {
    return fmaf(2.0f, frcp(1.0f + __expf(-2.0f * x)), -1.0f);  // overflow-safe
}
// LDS-visibility barrier that does NOT drain outstanding global loads.
__device__ __forceinline__ void lds_barrier() {
    asm volatile("s_waitcnt lgkmcnt(0)\n\ts_barrier" ::: "memory");
}

__global__ __launch_bounds__(256, 1)
void lstm_fused(const float* __restrict__ x, const float* __restrict__ Wih,
                const float* __restrict__ Whh, const float* __restrict__ bih,
                const float* __restrict__ bhh, const float* __restrict__ Wo,
                const float* __restrict__ bo, float* __restrict__ out)
{
    // xfrag: [g][c][64 fraglanes][8] bf16 per ts-group g (rows m=4ts'+b),
    // XOR-swizzled: byte off in g-slab = c*1024 + ((fraglane*16) ^ (c*32)).
    __shared__ unsigned short xfrag[2 * 2048];   // 8 KB
    // hfrag: [buf][16 rows][72] bf16 (pitch 72 shorts; rows 4-15 stay zero)
    __shared__ unsigned short hfrag[2 * 1152];   // 4.5 KB
    __shared__ float gbw[4 * 4 * 16 * 4];        // [w][q][l<16][r]   4 KB
    __shared__ float gxw[4 * 4 * 2 * 64 * 4];    // [w][q][g][lane][r] 32 KB
    __shared__ float hfin[4 * 64];               // final h fp32      1 KB

    const int tid  = threadIdx.x;
    const int lane = tid & 63;
    const int w    = tid >> 6;
    const int lq   = lane & 15;
    const int qd   = lane >> 4;
    const int b0   = blockIdx.x * BQ;

    // ---- weight B-fragments (constant over t; verified R2-R7 layout) ----
    short8 wih_f[4][4];
    short8 whh_f[4][2];
    float  bias[4];
    #pragma unroll
    for (int q = 0; q < 4; ++q) {
        const int n = 64 * q + 16 * w + lq;
        #pragma unroll
        for (int c = 0; c < 4; ++c) {
            const float* p = Wih + (size_t)n * D + 32 * c + 8 * qd;
            short8 v;
            #pragma unroll
            for (int j = 0; j < 8; ++j) v[j] = (short)f2bf(p[j]);
            wih_f[q][c] = v;
        }
        #pragma unroll
        for (int c = 0; c < 2; ++c) {
            const float* p = Whh + (size_t)n * H + 32 * c + 8 * qd;
            short8 v;
            #pragma unroll
            for (int j = 0; j < 8; ++j) v[j] = (short)f2bf(p[j]);
            whh_f[q][c] = v;
        }
        bias[q] = bih[n] + bhh[n];
    }

    // ---- staging geometry: thread stages row m=ms of each g-slab ----
    // m = 4*ts' + b  ->  b = ms&3, ts' = ms>>2
    const int ms    = tid >> 4;
    const int kslot = tid & 15;
    const int c_p   = kslot >> 2;
    const int q_p   = kslot & 3;
    const int l_p   = (q_p << 4) | ms;
    const int xoff  = c_p * 1024 + ((l_p * 16) ^ (c_p * 32));  // bytes in g-slab
    const int bb    = ms & 3, tsp = ms >> 2;
    const float* xbase = x + (size_t)(b0 + bb) * T * D + 8 * kslot;

    int xro[4];
    #pragma unroll
    for (int c = 0; c < 4; ++c) xro[c] = c * 1024 + ((lane * 16) ^ (c * 32));

    // ---- zero hfrag (rows 4-15 stay zero forever -> MFMA junk rows = 0) ----
    for (int i = tid; i < 1152; i += 256) ((unsigned int*)hfrag)[i] = 0;

    float4 pf[2][2];   // in-flight x loads for one chunk (2 g-groups)

    // prologue: xfrag=ch0 -> gx(ch0) -> xfrag=ch1, pf=ch2
    #pragma unroll
    for (int g = 0; g < 2; ++g) {
        const float* p = xbase + (size_t)(4 * g + tsp) * D;
        pf[g][0] = *(const float4*)p;
        pf[g][1] = *(const float4*)(p + 4);
    }
    #pragma unroll
    for (int g = 0; g < 2; ++g) {
        float4 a = pf[g][0], bv = pf[g][1];
        short8 v;
        v[0] = (short)f2bf(a.x);  v[1] = (short)f2bf(a.y);
        v[2] = (short)f2bf(a.z);  v[3] = (short)f2bf(a.w);
        v[4] = (short)f2bf(bv.x); v[5] = (short)f2bf(bv.y);
        v[6] = (short)f2bf(bv.z); v[7] = (short)f2bf(bv.w);
        *(short8*)((char*)xfrag + g * 4096 + xoff) = v;
    }
    #pragma unroll
    for (int g = 0; g < 2; ++g) {
        const float* p = xbase + (size_t)(TC + 4 * g + tsp) * D;
        pf[g][0] = *(const float4*)p;
        pf[g][1] = *(const float4*)(p + 4);
    }
    __syncthreads();

    float gxr[TC][4];   // gx in cell layout, 32 f32 regs

    // gx burst: ts-packed x-MFMAs + intra-wave round-trip (no barrier)
    auto gx_burst = [&]() {
        #pragma unroll
        for (int g = 0; g < 2; ++g) {
            short8 xf[4];
            #pragma unroll
            for (int c = 0; c < 4; ++c)
                xf[c] = *(const short8*)((char*)xfrag + g * 4096 + xro[c]);
            #pragma unroll
            for (int q = 0; q < 4; ++q) {
                f32x4 a = {bias[q], bias[q], bias[q], bias[q]};
                #pragma unroll
                for (int c = 0; c < 4; ++c)
                    a = __builtin_amdgcn_mfma_f32_16x16x32_bf16(xf[c], wih_f[q][c], a, 0, 0, 0);
                *(f32x4*)&gxw[(((w * 4 + q) * 2 + g) * 64 + lane) * 4] = a;
            }
        }
        // read back: gx(ts=tt, b=qd, j=16w+lq) = lane ((tt&3)<<4|lq), reg qd
        #pragma unroll
        for (int tt = 0; tt < TC; ++tt)
            #pragma unroll
            for (int q = 0; q < 4; ++q)
                gxr[tt][q] = gxw[(((w * 4 + q) * 2 + (tt >> 2)) * 64 +
                                  (((tt & 3) << 4) | lq)) * 4 + qd];
    };

    gx_burst();        // chunk 0
    lds_barrier();     // all waves done reading xfrag(ch0)
    #pragma unroll
    for (int g = 0; g < 2; ++g) {          // commit ch1
        float4 a = pf[g][0], bv = pf[g][1];
        short8 v;
        v[0] = (short)f2bf(a.x);  v[1] = (short)f2bf(a.y);
        v[2] = (short)f2bf(a.z);  v[3] = (short)f2bf(a.w);
        v[4] = (short)f2bf(bv.x); v[5] = (short)f2bf(bv.y);
        v[6] = (short)f2bf(bv.z); v[7] = (short)f2bf(bv.w);
        *(short8*)((char*)xfrag + g * 4096 + xoff) = v;
    }
    #pragma unroll
    for (int g = 0; g < 2; ++g) {          // issue ch2
        const float* p = xbase + (size_t)(2 * TC + 4 * g + tsp) * D;
        pf[g][0] = *(const float4*)p;
        pf[g][1] = *(const float4*)(p + 4);
    }

    float cst = 0.0f, hlast = 0.0f;

    for (int ch = 0; ch < NCH; ++ch) {
        #pragma unroll
        for (int tt = 0; tt < TC; ++tt) {
            const int hcur = tt & 1, hnxt = hcur ^ 1;

            short8 hfr[2];
            #pragma unroll
            for (int c = 0; c < 2; ++c)
                hfr[c] = *(const short8*)((char*)hfrag + hcur * 2304 +
                                          lq * 144 + c * 64 + qd * 16);
            f32x4 acc[4];
            #pragma unroll
            for (int q = 0; q < 4; ++q) {
                f32x4 a = {0.f, 0.f, 0.f, 0.f};
                #pragma unroll
                for (int c = 0; c < 2; ++c)
                    a = __builtin_amdgcn_mfma_f32_16x16x32_bf16(hfr[c], whh_f[q][c], a, 0, 0, 0);
                acc[q] = a;
            }

            // intra-wave redistribution: rows 0-3 live in lanes 0-15
            if (lane < 16) {
                #pragma unroll
                for (int q = 0; q < 4; ++q)
                    *(f32x4*)&gbw[((w * 4 + q) * 16 + lane) * 4] = acc[q];
            }
            // own cell (b=qd, j=16w+lq): gate q = gbw[w][q][lq][qd] + gx
            float gi = sigmoidf_(gbw[((w * 4 + 0) * 16 + lq) * 4 + qd] + gxr[tt][0]);
            float gf = sigmoidf_(gbw[((w * 4 + 1) * 16 + lq) * 4 + qd] + gxr[tt][1]);
            float gg = tanhf_  (gbw[((w * 4 + 2) * 16 + lq) * 4 + qd] + gxr[tt][2]);
            float go = sigmoidf_(gbw[((w * 4 + 3) * 16 + lq) * 4 + qd] + gxr[tt][3]);
            float c2 = fmaf(gf, cst, gi * gg);
            cst = c2;
            float hv = go * tanhf_(c2);
            hlast = hv;
            hfrag[hnxt * 1152 + qd * 72 + 16 * w + lq] = f2bf(hv);

            lds_barrier();   // h(t+1) visible to all waves
        }

        if (ch + 1 < NCH) {
            gx_burst();      // gx(ch+1) from xfrag (holds x(ch+1))
            lds_barrier();   // everyone done reading xfrag
            #pragma unroll
            for (int g = 0; g < 2; ++g) {      // commit x(ch+2)
                float4 a = pf[g][0], bv = pf[g][1];
                short8 v;
                v[0] = (short)f2bf(a.x);  v[1] = (short)f2bf(a.y);
                v[2] = (short)f2bf(a.z);  v[3] = (short)f2bf(a.w);
                v[4] = (short)f2bf(bv.x); v[5] = (short)f2bf(bv.y);
                v[6] = (short)f2bf(bv.z); v[7] = (short)f2bf(bv.w);
                *(short8*)((char*)xfrag + g * 4096 + xoff) = v;
            }
            const int ch3 = (ch + 3 < NCH) ? ch + 3 : NCH - 1;
            #pragma unroll
            for (int g = 0; g < 2; ++g) {      // issue x(ch+3)
                const float* p = xbase + ((size_t)ch3 * TC + 4 * g + tsp) * D;
                pf[g][0] = *(const float4*)p;
                pf[g][1] = *(const float4*)(p + 4);
            }
            // no barrier: 8 inner barriers of next chunk separate these
            // writes from the next boundary's reads
        }
    }

    // ---- epilogue: logits = relu(h) Wo^T + bo ; log_softmax over O=128 ----
    hfin[qd * 64 + 16 * w + lq] = hlast;
    __syncthreads();

    {
        const int m = w;                       // wave w handles batch w
        float l0 = bo[lane], l1 = bo[lane + 64];
        const float* w0 = Wo + (size_t)lane * H;
        const float* w1 = Wo + (size_t)(lane + 64) * H;
        #pragma unroll
        for (int k = 0; k < H; ++k) {
            float rh = fmaxf(hfin[m * 64 + k], 0.0f);
            l0 += rh * w0[k];
            l1 += rh * w1[k];
        }
        float mx = fmaxf(l0, l1);
        #pragma unroll
        for (int sh = 32; sh > 0; sh >>= 1) mx = fmaxf(mx, __shfl_xor(mx, sh));
        float e = __expf(l0 - mx) + __expf(l1 - mx);
        #pragma unroll
        for (int sh = 32; sh > 0; sh >>= 1) e += __shfl_xor(e, sh);
        float lse = mx + __logf(e);
        float* op = out + (size_t)(b0 + m) * O;
        op[lane]      = l0 - lse;
        op[lane + 64] = l1 - lse;
    }
}

extern "C" void kernel_launch(void* const* d_in, const int* in_sizes, int n_in,
                              void* d_out, int out_size, void* d_ws, size_t ws_size,
                              hipStream_t stream) {
    const float* x   = (const float*)d_in[0];
    const float* Wih = (const float*)d_in[1];
    const float* Whh = (const float*)d_in[2];
    const float* bih = (const float*)d_in[3];
    const float* bhh = (const float*)d_in[4];
    const float* Wo  = (const float*)d_in[5];
    const float* bo  = (const float*)d_in[6];
    lstm_fused<<<dim3(NBLK), dim3(256), 0, stream>>>(
        x, Wih, Whh, bih, bhh, Wo, bo, (float*)d_out);
}